// Round 9
// baseline (388.092 us; speedup 1.0000x reference)
//
#include <hip/hip_runtime.h>
#include <hip/hip_bf16.h>

#define MTOT 4096   // B*S
#define DD   1024
#define D2   2048
#define SS   2048
#define BB   2
#define NC2  64
#define CL2  (SS/NC2)   // 32

typedef __attribute__((ext_vector_type(8))) short bf16x8;
typedef __attribute__((ext_vector_type(4))) float f32x4;

__device__ __forceinline__ float sigmf(float v){
    return 1.0f/(1.0f+__expf(-v));
}
__device__ __forceinline__ float geluf(float v){
    float u = 0.7978845608f*v*(1.0f + 0.044715f*v*v);
    float e = __expf(2.0f*u);
    float t = 1.0f - 2.0f/(e + 1.0f);
    return 0.5f*v*(1.0f + t);
}
__device__ __forceinline__ ushort f2bf(float f){
    unsigned u = __float_as_uint(f);
    unsigned r = (u + 0x7FFF + ((u>>16)&1)) >> 16;
    return (ushort)r;
}
__device__ __forceinline__ float bf2f(ushort u){
    return __uint_as_float(((unsigned)u)<<16);
}

// ================= 128x128 core (round-6, proven; BC + heads) ======
__device__ __forceinline__ void stage_tile(
    const ushort* __restrict__ A, const ushort* __restrict__ Bt, int K,
    int m0, int n0, int k0, ushort* As, ushort* Bs)
{
    int tid = threadIdx.x;
    #pragma unroll
    for (int i = 0; i < 2; i++) {
        int e = (i*256 + tid) * 8;          // elem in [128][32] tile (linear LDS)
        int r = e >> 5;
        int s = (e >> 3) & 3;
        int c = ((s ^ ((r >> 1) & 3)) << 3);   // inverse-swizzled source col
        __builtin_amdgcn_global_load_lds(
            (const __attribute__((address_space(1))) void*)(A + (size_t)(m0 + r)*K + k0 + c),
            (__attribute__((address_space(3))) void*)(As + e), 16, 0, 0);
        __builtin_amdgcn_global_load_lds(
            (const __attribute__((address_space(1))) void*)(Bt + (size_t)(n0 + r)*K + k0 + c),
            (__attribute__((address_space(3))) void*)(Bs + e), 16, 0, 0);
    }
}

__device__ __forceinline__ void load_frags(
    const ushort* As, const ushort* Bs, int wr, int wc, int lrow, int cs,
    bf16x8 (&af)[4], bf16x8 (&bfr)[4])
{
    #pragma unroll
    for (int i = 0; i < 4; i++) {
        int ra = wr*64 + i*16 + lrow;
        int rb = wc*64 + i*16 + lrow;
        af[i]  = *(const bf16x8*)(As + ra*32 + ((cs ^ ((ra>>1)&3))<<3));
        bfr[i] = *(const bf16x8*)(Bs + rb*32 + ((cs ^ ((rb>>1)&3))<<3));
    }
}

__device__ __forceinline__ void do_mfma(
    const bf16x8 (&af)[4], const bf16x8 (&bfr)[4], f32x4 (&acc)[4][4])
{
    __builtin_amdgcn_s_setprio(1);
    #pragma unroll
    for (int i = 0; i < 4; i++)
        #pragma unroll
        for (int j = 0; j < 4; j++)
            acc[i][j] = __builtin_amdgcn_mfma_f32_16x16x32_bf16(af[i], bfr[j], acc[i][j], 0, 0, 0);
    __builtin_amdgcn_s_setprio(0);
}

__device__ __forceinline__ void mgemm_core(
    const ushort* __restrict__ A, const ushort* __restrict__ Bt, int K,
    int m0, int n0, ushort (&As)[2][4096], ushort (&Bs)[2][4096], f32x4 (&acc)[4][4])
{
    int lane = threadIdx.x & 63, wave = threadIdx.x >> 6;
    int wr = wave >> 1, wc = wave & 1;
    int lrow = lane & 15, cs = lane >> 4;
    int NT = K >> 5;
    stage_tile(A, Bt, K, m0, n0, 0,  As[0], Bs[0]);
    stage_tile(A, Bt, K, m0, n0, 32, As[1], Bs[1]);
    for (int t = 0; t < NT-1; ++t) {
        asm volatile("s_waitcnt vmcnt(4)" ::: "memory");
        __builtin_amdgcn_s_barrier();
        bf16x8 af[4], bfr[4];
        load_frags(As[t&1], Bs[t&1], wr, wc, lrow, cs, af, bfr);
        if (t < NT-2) {
            asm volatile("s_waitcnt lgkmcnt(0)" ::: "memory");
            __builtin_amdgcn_s_barrier();
            stage_tile(A, Bt, K, m0, n0, (t+2) << 5, As[t&1], Bs[t&1]);
        }
        __builtin_amdgcn_sched_barrier(0);
        do_mfma(af, bfr, acc);
    }
    asm volatile("s_waitcnt vmcnt(0)" ::: "memory");
    __builtin_amdgcn_s_barrier();
    bf16x8 af[4], bfr[4];
    load_frags(As[(NT-1)&1], Bs[(NT-1)&1], wr, wc, lrow, cs, af, bfr);
    do_mfma(af, bfr, acc);
}

// ================= 256x256 core, BK=64, depth-2, PHASED frag reads =======
// LDS tile [256][64] bf16 (128-B rows). 8-slot XOR swizzle phys=slot^(row&7),
// both-sides (inverse-swizzled global source + swizzled ds_read).
__device__ __forceinline__ void stage64(
    const ushort* __restrict__ A, const ushort* __restrict__ Bt, int K,
    int m0, int n0, int k0, ushort* As, ushort* Bs)
{
    int tid = threadIdx.x;
    #pragma unroll
    for (int i = 0; i < 4; i++) {
        int e = (i*512 + tid) * 8;          // elem in [256][64] tile (linear LDS)
        int r = e >> 6;
        int s = (e >> 3) & 7;
        int c = (s ^ (r & 7)) << 3;         // inverse-swizzled source col
        __builtin_amdgcn_global_load_lds(
            (const __attribute__((address_space(1))) void*)(A + (size_t)(m0 + r)*K + k0 + c),
            (__attribute__((address_space(3))) void*)(As + e), 16, 0, 0);
        __builtin_amdgcn_global_load_lds(
            (const __attribute__((address_space(1))) void*)(Bt + (size_t)(n0 + r)*K + k0 + c),
            (__attribute__((address_space(3))) void*)(Bs + e), 16, 0, 0);
    }
}

// Fused GEMM A: xb @ [w_pt1 | w_wg | w_mag | w_q1 | w_mix], M=4096 N=7168 K=1024.
// 448 blocks x 512 threads; 8 waves (2m x 4n), wave tile 128x64.
// Per K-tile: 4 phases {ds_read 4 A-frags (+4 B-frags per ks) -> 16 MFMA};
// max 48 frag VGPRs live (r7/r8 spilled holding all 96).
__global__ __launch_bounds__(512,2) void mgemmA256_k(
    const ushort* __restrict__ xb, const ushort* __restrict__ Wt,
    const float* __restrict__ b_pt1, const float* __restrict__ b_wg,
    const float* __restrict__ b_mag, const float* __restrict__ b_q1,
    const float* __restrict__ b_mix, const float* __restrict__ gtemp,
    ushort* __restrict__ H1b, ushort* __restrict__ wgb, ushort* __restrict__ magb,
    ushort* __restrict__ Hqb, ushort* __restrict__ mixb)
{
    __shared__ ushort As[2][16384], Bs[2][16384];   // 128 KB
    const int K = 1024, NT = 16;                    // NT = K/64
    int bid = blockIdx.x;
    int xcd = bid & 7, local = bid >> 3;            // 56 per XCD
    int m0 = (xcd*2 + (local & 1)) * 256;           // A-panel L2-resident per XCD
    int n0 = (local >> 1) * 256;                    // 28 n-panels
    int lane = threadIdx.x & 63, wave = threadIdx.x >> 6;
    int wr = wave >> 2, wc = wave & 3;              // 2 x 4 wave grid
    int lrow = lane & 15, cs = lane >> 4;
    f32x4 acc[8][4] = {};
    stage64(xb, Wt, K, m0, n0, 0,  As[0], Bs[0]);   // 8 loads/thread
    stage64(xb, Wt, K, m0, n0, 64, As[1], Bs[1]);   // 16 outstanding
    for (int t = 0; t < NT; ++t) {
        if (t < NT-1) { asm volatile("s_waitcnt vmcnt(8)" ::: "memory"); }
        else          { asm volatile("s_waitcnt vmcnt(0)" ::: "memory"); }
        __builtin_amdgcn_s_barrier();
        const ushort* Ab = As[t&1];
        const ushort* Bb = Bs[t&1];
        #pragma unroll
        for (int ks = 0; ks < 2; ++ks) {
            bf16x8 bfr[4];
            #pragma unroll
            for (int j = 0; j < 4; j++) {
                int rb = wc*64 + j*16 + lrow;
                int phys = (ks*4 + cs) ^ (rb & 7);
                bfr[j] = *(const bf16x8*)(Bb + rb*64 + phys*8);
            }
            #pragma unroll
            for (int half = 0; half < 2; ++half) {
                bf16x8 af[4];
                #pragma unroll
                for (int i = 0; i < 4; i++) {
                    int ra = wr*128 + (half*4 + i)*16 + lrow;
                    int phys = (ks*4 + cs) ^ (ra & 7);
                    af[i] = *(const bf16x8*)(Ab + ra*64 + phys*8);
                }
                asm volatile("s_waitcnt lgkmcnt(0)" ::: "memory");
                __builtin_amdgcn_sched_barrier(0);
                __builtin_amdgcn_s_setprio(1);
                #pragma unroll
                for (int i = 0; i < 4; i++)
                    #pragma unroll
                    for (int j = 0; j < 4; j++)
                        acc[half*4+i][j] = __builtin_amdgcn_mfma_f32_16x16x32_bf16(
                            af[i], bfr[j], acc[half*4+i][j], 0, 0, 0);
                __builtin_amdgcn_s_setprio(0);
            }
        }
        __builtin_amdgcn_s_barrier();          // all waves done reading buf[t&1]
        if (t < NT-2)
            stage64(xb, Wt, K, m0, n0, (t+2) << 6, As[t&1], Bs[t&1]);
    }

    // epilogue
    int rng = n0 >> 10;           // 0,1:pt1  2:wg  3:mag  4:q1  5,6:mix
    float gt = gtemp[0];
    #pragma unroll
    for (int i = 0; i < 8; i++) {
        int mb = m0 + wr*128 + i*16 + (lane>>4)*4;
        #pragma unroll
        for (int j = 0; j < 4; j++) {
            int n = n0 + wc*64 + j*16 + (lane&15);
            #pragma unroll
            for (int r = 0; r < 4; r++) {
                int m = mb + r;
                float v = acc[i][j][r];
                if (rng < 2) {
                    H1b[(size_t)m*D2 + n] = f2bf(geluf(v + b_pt1[n]));
                } else if (rng == 2) {
                    wgb[(size_t)m*DD + n-2048] = f2bf(sigmf((v + b_wg[n-2048])*gt));
                } else if (rng == 3) {
                    magb[(size_t)m*DD + n-3072] = f2bf(sigmf(v + b_mag[n-3072])*5.0f);
                } else if (rng == 4) {
                    Hqb[(size_t)m*DD + n-4096] = f2bf(geluf(v + b_q1[n-4096]));
                } else {
                    mixb[(size_t)m*D2 + n-5120] = f2bf(sigmf(v + b_mix[n-5120]));
                }
            }
        }
    }
}

// z=0: pd = bf16((H1 @ w_pt2 + b_pt2) * |iscale|) (K=2048)
// z=1: qadj = bf16(Hq @ w_q2 + b_q2)              (K=1024)
__global__ __launch_bounds__(256,4) void mgemmBC_k(
    const ushort* __restrict__ H1b, const ushort* __restrict__ wt_pt2,
    const ushort* __restrict__ Hqb, const ushort* __restrict__ wt_q2,
    const float* __restrict__ b_pt2, const float* __restrict__ b_q2,
    const float* __restrict__ iscale,
    ushort* __restrict__ pdb, ushort* __restrict__ qadjb)
{
    __shared__ ushort As[2][4096], Bs[2][4096];
    int bid = blockIdx.x;
    int xcd = bid & 7, local = bid >> 3;          // [0,64)
    int m0 = (xcd*4 + (local & 3)) * 128;
    int rest = local >> 2;                        // [0,16)
    int z = rest >> 3;
    int n0 = (rest & 7) * 128;
    const ushort* A  = z ? Hqb   : H1b;
    const ushort* Bt = z ? wt_q2 : wt_pt2;
    const float* bias = z ? b_q2 : b_pt2;
    int K = z ? 1024 : 2048;
    ushort* outp = z ? qadjb : pdb;
    f32x4 acc[4][4] = {};
    mgemm_core(A, Bt, K, m0, n0, As, Bs, acc);
    int lane = threadIdx.x & 63, wave = threadIdx.x >> 6;
    int wr = wave >> 1, wc = wave & 1;
    #pragma unroll
    for (int i = 0; i < 4; i++) {
        int mb = m0 + wr*64 + i*16 + (lane>>4)*4;
        #pragma unroll
        for (int j = 0; j < 4; j++) {
            int n = n0 + wc*64 + j*16 + (lane&15);
            float bv = bias[n];
            float sc = z ? 1.0f : fabsf(iscale[n]);
            #pragma unroll
            for (int r = 0; r < 4; r++) {
                float v = acc[i][j][r] + bv;
                outp[(size_t)(mb+r)*DD + n] = f2bf(z ? v : v*sc);
            }
        }
    }
}

// head GEMMs; 1D grid 256
template<int ACT, bool RESID, bool OUTBF16>
__global__ __launch_bounds__(256,4) void mgemm_k(
    const ushort* __restrict__ A, const ushort* __restrict__ Bt,
    const float* __restrict__ bias, const float* __restrict__ resid,
    void* __restrict__ Cout, int N, int K)
{
    __shared__ ushort As[2][4096], Bs[2][4096];
    int bid = blockIdx.x;
    int xcd = bid & 7, local = bid >> 3;          // [0,32)
    int m0 = (xcd*4 + (local & 3)) * 128;
    int n0 = (local >> 2) * 128;                  // 8 n-panels
    f32x4 acc[4][4] = {};
    mgemm_core(A, Bt, K, m0, n0, As, Bs, acc);
    int lane = threadIdx.x & 63, wave = threadIdx.x >> 6;
    int wr = wave >> 1, wc = wave & 1;
    #pragma unroll
    for (int i = 0; i < 4; i++) {
        int mb = m0 + wr*64 + i*16 + (lane>>4)*4;
        #pragma unroll
        for (int j = 0; j < 4; j++) {
            int n = n0 + wc*64 + j*16 + (lane&15);
            float bv = bias[n];
            #pragma unroll
            for (int r = 0; r < 4; r++) {
                size_t idx = (size_t)(mb + r)*N + n;
                float v = acc[i][j][r] + bv;
                if (ACT==1) v = geluf(v);
                if (RESID) v += resid[idx];
                if (OUTBF16) ((ushort*)Cout)[idx] = f2bf(v);
                else         ((float*)Cout)[idx]  = v;
            }
        }
    }
}

// ---------------- conversions ----------------
__global__ __launch_bounds__(256) void cvt_bf16_k(const float* __restrict__ in, ushort* __restrict__ outp){
    size_t i = ((size_t)blockIdx.x*256 + threadIdx.x)*8;
    float4 a = *(const float4*)(in + i);
    float4 b = *(const float4*)(in + i + 4);
    ushort t[8];
    t[0]=f2bf(a.x); t[1]=f2bf(a.y); t[2]=f2bf(a.z); t[3]=f2bf(a.w);
    t[4]=f2bf(b.x); t[5]=f2bf(b.y); t[6]=f2bf(b.z); t[7]=f2bf(b.w);
    *(int4*)(outp + i) = *(const int4*)t;
}

__device__ __forceinline__ void tcvt_body(const float* W, ushort* Wt, int K, int N){
    __shared__ float tile[32][33];
    int n0 = blockIdx.x*32, k0 = blockIdx.y*32;
    int tx = threadIdx.x & 7, ty = threadIdx.x >> 3;
    float4 v = *(const float4*)(W + (size_t)(k0+ty)*N + n0 + tx*4);
    tile[ty][tx*4+0]=v.x; tile[ty][tx*4+1]=v.y; tile[ty][tx*4+2]=v.z; tile[ty][tx*4+3]=v.w;
    __syncthreads();
    ushort t[4];
    #pragma unroll
    for (int i=0;i<4;i++) t[i] = f2bf(tile[tx*4+i][ty]);
    *(uint2*)(Wt + (size_t)(n0+ty)*K + k0 + tx*4) = *(const uint2*)t;
}

__global__ __launch_bounds__(256) void tcvt_k(const float* __restrict__ W, ushort* __restrict__ Wt, int K, int N){
    tcvt_body(W, Wt, K, N);
}
__global__ __launch_bounds__(256) void tcvt2_k(const float* __restrict__ w0, ushort* __restrict__ o0,
                                               const float* __restrict__ w1, ushort* __restrict__ o1){
    tcvt_body(blockIdx.z ? w1 : w0, blockIdx.z ? o1 : o0, 1024, 2048);
}
__global__ __launch_bounds__(256) void tcvt6_k(
    const float* __restrict__ w0, ushort* __restrict__ o0,
    const float* __restrict__ w1, ushort* __restrict__ o1,
    const float* __restrict__ w2, ushort* __restrict__ o2,
    const float* __restrict__ w3, ushort* __restrict__ o3,
    const float* __restrict__ w4, ushort* __restrict__ o4,
    const float* __restrict__ w5, ushort* __restrict__ o5)
{
    const float* W; ushort* Wt;
    switch(blockIdx.z){
        case 0: W=w0; Wt=o0; break;
        case 1: W=w1; Wt=o1; break;
        case 2: W=w2; Wt=o2; break;
        case 3: W=w3; Wt=o3; break;
        case 4: W=w4; Wt=o4; break;
        default: W=w5; Wt=o5; break;
    }
    tcvt_body(W, Wt, 1024, 1024);
}

// ---------------- scan complex (recompute-on-the-fly, 2 d-cols/thread) ----
__global__ __launch_bounds__(256) void passA_k(
    const ushort* __restrict__ pdb, float* __restrict__ csum)
{
    int d0 = (blockIdx.x*256 + threadIdx.x)*2;
    int c = blockIdx.y, b = blockIdx.z;
    const ushort* p = pdb + ((size_t)b*SS + (size_t)c*CL2)*DD + d0;
    float s0 = 0.f, s1 = 0.f;
    for (int i = 0; i < CL2; i++){
        ushort2 v = *(const ushort2*)(p + (size_t)i*DD);
        s0 += bf2f(v.x); s1 += bf2f(v.y);
    }
    *(float2*)(csum + ((size_t)b*NC2 + c)*DD + d0) = make_float2(s0, s1);
}

__global__ void scan2_k(float* __restrict__ csum, int nchains){
    int idx = blockIdx.x*256 + threadIdx.x;
    if (idx >= nchains) return;
    int xg = idx / DD, d = idx % DD;
    float* p = csum + (size_t)xg*NC2*DD + d;
    float run = 0.f;
    for (int c = 0; c < NC2; c++){ float t = p[(size_t)c*DD]; p[(size_t)c*DD] = run; run += t; }
}

__global__ __launch_bounds__(256) void passB_k(
    const ushort* __restrict__ pdb, const ushort* __restrict__ wgb,
    const ushort* __restrict__ magb, const ushort* __restrict__ xb,
    const float* __restrict__ csum_phi, float* __restrict__ csum_tri)
{
    int d0 = (blockIdx.x*256 + threadIdx.x)*2;
    int c = blockIdx.y, b = blockIdx.z;
    size_t off = ((size_t)b*SS + (size_t)c*CL2)*DD + d0;
    float2 phv = *(const float2*)(csum_phi + ((size_t)b*NC2 + c)*DD + d0);
    float ph0 = phv.x, ph1 = phv.y;
    float a0=0.f, a1=0.f, b0=0.f, b1=0.f, c0=0.f, c1=0.f;
    for (int i = 0; i < CL2; i++){
        size_t o = off + (size_t)i*DD;
        ushort2 pdv = *(const ushort2*)(pdb + o);
        ushort2 wgv = *(const ushort2*)(wgb + o);
        ushort2 mgv = *(const ushort2*)(magb + o);
        ushort2 xv  = *(const ushort2*)(xb + o);
        ph0 += bf2f(pdv.x); ph1 += bf2f(pdv.y);
        float w0 = bf2f(wgv.x), w1 = bf2f(wgv.y);
        float m0 = bf2f(mgv.x), m1 = bf2f(mgv.y);
        float ct0 = w0*bf2f(xv.x)*m0, ct1 = w1*bf2f(xv.y)*m1;
        float sp0, cp0, sp1, cp1;
        sincosf(ph0, &sp0, &cp0); sincosf(ph1, &sp1, &cp1);
        a0 += ct0*cp0; a1 += ct1*cp1;
        b0 += ct0*sp0; b1 += ct1*sp1;
        c0 += fmaf(w0, m0, 1e-8f); c1 += fmaf(w1, m1, 1e-8f);
    }
    size_t cs = ((size_t)b*NC2 + c)*DD + d0;
    size_t G = (size_t)BB*NC2*DD;
    *(float2*)(csum_tri + cs)     = make_float2(a0, a1);
    *(float2*)(csum_tri + G+cs)   = make_float2(b0, b1);
    *(float2*)(csum_tri + 2*G+cs) = make_float2(c0, c1);
}

__global__ __launch_bounds__(256) void passC_k(
    const ushort* __restrict__ pdb, const ushort* __restrict__ wgb,
    const ushort* __restrict__ magb, const ushort* __restrict__ xb,
    const ushort* __restrict__ qadjb, const ushort* __restrict__ mixb,
    const float* __restrict__ csum_phi, const float* __restrict__ csum_tri,
    ushort* __restrict__ ret)
{
    int d0 = (blockIdx.x*256 + threadIdx.x)*2;
    int c = blockIdx.y, b = blockIdx.z;
    size_t off = ((size_t)b*SS + (size_t)c*CL2)*DD + d0;
    size_t cs = ((size_t)b*NC2 + c)*DD + d0;
    size_t G = (size_t)BB*NC2*DD;
    float2 phv = *(const float2*)(csum_phi + cs);
    float2 r0v = *(const float2*)(csum_tri + cs);
    float2 r1v = *(const float2*)(csum_tri + G+cs);
    float2 r2v = *(const float2*)(csum_tri + 2*G+cs);
    float ph0 = phv.x, ph1 = phv.y;
    float p0 = r0v.x, p1 = r0v.y, q0 = r1v.x, q1 = r1v.y, s0 = r2v.x, s1 = r2v.y;
    size_t row0 = (size_t)b*SS + (size_t)c*CL2;
    for (int i = 0; i < CL2; i++){
        size_t o = off + (size_t)i*DD;
        ushort2 pdv = *(const ushort2*)(pdb + o);
        ushort2 wgv = *(const ushort2*)(wgb + o);
        ushort2 mgv = *(const ushort2*)(magb + o);
        ushort2 xv  = *(const ushort2*)(xb + o);
        ushort2 qav = *(const ushort2*)(qadjb + o);
        size_t mb2 = (row0 + i)*D2 + d0;
        ushort2 mrv = *(const ushort2*)(mixb + mb2);
        ushort2 miv = *(const ushort2*)(mixb + mb2 + DD);
        ph0 += bf2f(pdv.x); ph1 += bf2f(pdv.y);
        float w0 = bf2f(wgv.x), w1 = bf2f(wgv.y);
        float m0 = bf2f(mgv.x), m1 = bf2f(mgv.y);
        float ct0 = w0*bf2f(xv.x)*m0, ct1 = w1*bf2f(xv.y)*m1;
        float sp0, cp0, sp1, cp1;
        sincosf(ph0, &sp0, &cp0); sincosf(ph1, &sp1, &cp1);
        p0 += ct0*cp0; p1 += ct1*cp1;
        q0 += ct0*sp0; q1 += ct1*sp1;
        s0 += fmaf(w0, m0, 1e-8f); s1 += fmaf(w1, m1, 1e-8f);
        float inv0 = rsqrtf(s0), inv1 = rsqrtf(s1);
        float mr0 = p0*inv0, mi0 = q0*inv0;
        float mr1 = p1*inv1, mi1 = q1*inv1;
        float sq0, cq0, sq1, cq1;
        sincosf(ph0 + bf2f(qav.x), &sq0, &cq0);
        sincosf(ph1 + bf2f(qav.y), &sq1, &cq1);
        float rr0 = mr0*cq0 + mi0*sq0, ri0 = mi0*cq0 - mr0*sq0;
        float rr1 = mr1*cq1 + mi1*sq1, ri1 = mi1*cq1 - mr1*sq1;
        ushort2 rv;
        rv.x = f2bf(bf2f(mrv.x)*rr0 + bf2f(miv.x)*ri0);
        rv.y = f2bf(bf2f(mrv.y)*rr1 + bf2f(miv.y)*ri1);
        *(ushort2*)(ret + o) = rv;
    }
}

// LayerNorm over d per row; bf16 in/out, ushort4 vectorized
__global__ __launch_bounds__(256) void ln_k(
    const ushort* __restrict__ ret, const float* __restrict__ ln_g,
    const float* __restrict__ ln_b, ushort* __restrict__ outp)
{
    int row = blockIdx.x;
    size_t base = (size_t)row*DD;
    int d0 = threadIdx.x*4;
    ushort4 rv = *(const ushort4*)(ret + base + d0);
    float v0 = bf2f(rv.x), v1 = bf2f(rv.y), v2 = bf2f(rv.z), v3 = bf2f(rv.w);
    float sum = v0+v1+v2+v3;
    float sumsq = v0*v0 + v1*v1 + v2*v2 + v3*v3;
    #pragma unroll
    for (int off=32; off; off>>=1){
        sum   += __shfl_down(sum,off);
        sumsq += __shfl_down(sumsq,off);
    }
    __shared__ float red[8];
    int lane = threadIdx.x & 63, wid = threadIdx.x >> 6;
    if (lane==0){ red[wid]=sum; red[4+wid]=sumsq; }
    __syncthreads();
    sum   = red[0]+red[1]+red[2]+red[3];
    sumsq = red[4]+red[5]+red[6]+red[7];
    float mu  = sum * (1.0f/DD);
    float var = sumsq*(1.0f/DD) - mu*mu;
    float rstd = rsqrtf(var + 1e-5f);
    float4 g = *(const float4*)(ln_g + d0);
    float4 bb = *(const float4*)(ln_b + d0);
    ushort4 ov;
    ov.x = f2bf((v0-mu)*rstd*g.x + bb.x);
    ov.y = f2bf((v1-mu)*rstd*g.y + bb.y);
    ov.z = f2bf((v2-mu)*rstd*g.z + bb.z);
    ov.w = f2bf((v3-mu)*rstd*g.w + bb.w);
    *(ushort4*)(outp + base + d0) = ov;
}

extern "C" void kernel_launch(void* const* d_in, const int* in_sizes, int n_in,
                              void* d_out, int out_size, void* d_ws, size_t ws_size,
                              hipStream_t stream)
{
    const float* x     = (const float*)d_in[0];
    const float* w_pt1 = (const float*)d_in[1];
    const float* b_pt1 = (const float*)d_in[2];
    const float* w_pt2 = (const float*)d_in[3];
    const float* b_pt2 = (const float*)d_in[4];
    const float* iscale= (const float*)d_in[5];
    const float* w_wg  = (const float*)d_in[6];
    const float* b_wg  = (const float*)d_in[7];
    const float* gtemp = (const float*)d_in[8];
    const float* w_mag = (const float*)d_in[9];
    const float* b_mag = (const float*)d_in[10];
    const float* w_q1  = (const float*)d_in[11];
    const float* b_q1  = (const float*)d_in[12];
    const float* w_q2  = (const float*)d_in[13];
    const float* b_q2  = (const float*)d_in[14];
    const float* w_mix = (const float*)d_in[15];
    const float* b_mix = (const float*)d_in[16];
    const float* ln_g  = (const float*)d_in[17];
    const float* ln_b  = (const float*)d_in[18];
    const float* w_o1  = (const float*)d_in[19];
    const float* b_o1  = (const float*)d_in[20];
    const float* w_o2  = (const float*)d_in[21];
    const float* b_o2  = (const float*)d_in[22];
    float* out = (float*)d_out;

    const size_t SZ = (size_t)MTOT*DD;     // 4M elems
    ushort* u = (ushort*)d_ws;
    ushort* xb    = u;                 u += SZ;        // bf16 x
    ushort* H1b   = u;                 u += 2*SZ;      // [4096][2048]
    ushort* ret   = H1b;                                // alias (H1b dead after BC)
    ushort* Hqb   = u;                 u += SZ;
    ushort* lnb   = Hqb;                                // alias (Hqb dead after BC)
    ushort* wgb   = u;                 u += SZ;
    ushort* magb  = u;                 u += SZ;
    ushort* mixb  = u;                 u += 2*SZ;      // [4096][2048]
    ushort* Hob   = u;                 u += SZ;
    ushort* pdb   = u;                 u += SZ;        // bf16
    ushort* qadjb = u;                 u += SZ;        // bf16
    ushort* Wt_all= u;                 u += (size_t)7168*1024;
    ushort* wt_pt2= u;                 u += (size_t)1024*2048;
    ushort* wt_q2 = u;                 u += (size_t)1024*1024;
    ushort* wt_o1 = u;                 u += (size_t)1024*1024;
    ushort* wt_o2 = u;                 u += (size_t)1024*1024;
    float* csum_phi = (float*)u;                       // BB*NC2*DD
    float* csum_tri = csum_phi + (size_t)BB*NC2*DD;    // 3x

    dim3 blk(256);
    // conversions
    cvt_bf16_k<<<dim3(SZ/2048), blk, 0, stream>>>(x, xb);
    tcvt2_k<<<dim3(64, 32, 2), blk, 0, stream>>>(w_pt1, Wt_all, w_mix, Wt_all + (size_t)5120*1024);
    tcvt6_k<<<dim3(32, 32, 6), blk, 0, stream>>>(
        w_wg,  Wt_all + (size_t)2048*1024,
        w_mag, Wt_all + (size_t)3072*1024,
        w_q1,  Wt_all + (size_t)4096*1024,
        w_q2,  wt_q2,  w_o1, wt_o1,  w_o2, wt_o2);
    tcvt_k<<<dim3(32, 64), blk, 0, stream>>>(w_pt2, wt_pt2, 2048, 1024);
    // fused GEMM A: 256x256 BK=64 depth-2, phased frag reads (448 x 512)
    mgemmA256_k<<<dim3(448), dim3(512), 0, stream>>>(xb, Wt_all, b_pt1, b_wg, b_mag, b_q1, b_mix,
                                                     gtemp, H1b, wgb, magb, Hqb, mixb);
    // GEMM B/C (512 blocks)
    mgemmBC_k<<<dim3(512), blk, 0, stream>>>(H1b, wt_pt2, Hqb, wt_q2, b_pt2, b_q2,
                                             iscale, pdb, qadjb);
    // scan complex
    passA_k<<<dim3(DD/512, NC2, BB), blk, 0, stream>>>(pdb, csum_phi);
    scan2_k<<<dim3((BB*DD+255)/256), blk, 0, stream>>>(csum_phi, BB*DD);
    passB_k<<<dim3(DD/512, NC2, BB), blk, 0, stream>>>(pdb, wgb, magb, xb, csum_phi, csum_tri);
    scan2_k<<<dim3((3*BB*DD+255)/256), blk, 0, stream>>>(csum_tri, 3*BB*DD);
    passC_k<<<dim3(DD/512, NC2, BB), blk, 0, stream>>>(pdb, wgb, magb, xb, qadjb, mixb,
                                                       csum_phi, csum_tri, ret);
    ln_k<<<dim3(MTOT), blk, 0, stream>>>(ret, ln_g, ln_b, lnb);
    // output head (256 blocks each)
    mgemm_k<1,false,true><<<dim3(256), blk, 0, stream>>>(lnb, wt_o1, b_o1, nullptr, Hob, DD, DD);
    mgemm_k<0,true,false><<<dim3(256), blk, 0, stream>>>(Hob, wt_o2, b_o2, x, out, DD, DD);
}

// Round 10
// 253.553 us; speedup vs baseline: 1.5306x; 1.5306x over previous
//
#include <hip/hip_runtime.h>
#include <hip/hip_bf16.h>

#define MTOT 4096   // B*S
#define DD   1024
#define D2   2048
#define SS   2048
#define BB   2
#define NC2  64
#define CL2  (SS/NC2)   // 32

typedef __attribute__((ext_vector_type(8))) short bf16x8;
typedef __attribute__((ext_vector_type(4))) float f32x4;

__device__ __forceinline__ float sigmf(float v){
    return 1.0f/(1.0f+__expf(-v));
}
__device__ __forceinline__ float geluf(float v){
    float u = 0.7978845608f*v*(1.0f + 0.044715f*v*v);
    float e = __expf(2.0f*u);
    float t = 1.0f - 2.0f/(e + 1.0f);
    return 0.5f*v*(1.0f + t);
}
__device__ __forceinline__ ushort f2bf(float f){
    unsigned u = __float_as_uint(f);
    unsigned r = (u + 0x7FFF + ((u>>16)&1)) >> 16;
    return (ushort)r;
}
__device__ __forceinline__ float bf2f(ushort u){
    return __uint_as_float(((unsigned)u)<<16);
}

// ================= 128x128 core (round-6, proven) ======
// BK=32, depth-2 counted-vmcnt pipeline, 8-elem XOR swizzle (2-way free),
// both-sides rule: linear LDS dest + inverse-swizzled global src + swizzled read.
__device__ __forceinline__ void stage_tile(
    const ushort* __restrict__ A, const ushort* __restrict__ Bt, int K,
    int m0, int n0, int k0, ushort* As, ushort* Bs)
{
    int tid = threadIdx.x;
    #pragma unroll
    for (int i = 0; i < 2; i++) {
        int e = (i*256 + tid) * 8;          // elem in [128][32] tile (linear LDS)
        int r = e >> 5;
        int s = (e >> 3) & 3;
        int c = ((s ^ ((r >> 1) & 3)) << 3);   // inverse-swizzled source col
        __builtin_amdgcn_global_load_lds(
            (const __attribute__((address_space(1))) void*)(A + (size_t)(m0 + r)*K + k0 + c),
            (__attribute__((address_space(3))) void*)(As + e), 16, 0, 0);
        __builtin_amdgcn_global_load_lds(
            (const __attribute__((address_space(1))) void*)(Bt + (size_t)(n0 + r)*K + k0 + c),
            (__attribute__((address_space(3))) void*)(Bs + e), 16, 0, 0);
    }
}

__device__ __forceinline__ void load_frags(
    const ushort* As, const ushort* Bs, int wr, int wc, int lrow, int cs,
    bf16x8 (&af)[4], bf16x8 (&bfr)[4])
{
    #pragma unroll
    for (int i = 0; i < 4; i++) {
        int ra = wr*64 + i*16 + lrow;
        int rb = wc*64 + i*16 + lrow;
        af[i]  = *(const bf16x8*)(As + ra*32 + ((cs ^ ((ra>>1)&3))<<3));
        bfr[i] = *(const bf16x8*)(Bs + rb*32 + ((cs ^ ((rb>>1)&3))<<3));
    }
}

__device__ __forceinline__ void do_mfma(
    const bf16x8 (&af)[4], const bf16x8 (&bfr)[4], f32x4 (&acc)[4][4])
{
    __builtin_amdgcn_s_setprio(1);
    #pragma unroll
    for (int i = 0; i < 4; i++)
        #pragma unroll
        for (int j = 0; j < 4; j++)
            acc[i][j] = __builtin_amdgcn_mfma_f32_16x16x32_bf16(af[i], bfr[j], acc[i][j], 0, 0, 0);
    __builtin_amdgcn_s_setprio(0);
}

__device__ __forceinline__ void mgemm_core(
    const ushort* __restrict__ A, const ushort* __restrict__ Bt, int K,
    int m0, int n0, ushort (&As)[2][4096], ushort (&Bs)[2][4096], f32x4 (&acc)[4][4])
{
    int lane = threadIdx.x & 63, wave = threadIdx.x >> 6;
    int wr = wave >> 1, wc = wave & 1;
    int lrow = lane & 15, cs = lane >> 4;
    int NT = K >> 5;
    stage_tile(A, Bt, K, m0, n0, 0,  As[0], Bs[0]);
    stage_tile(A, Bt, K, m0, n0, 32, As[1], Bs[1]);
    for (int t = 0; t < NT-1; ++t) {
        asm volatile("s_waitcnt vmcnt(4)" ::: "memory");
        __builtin_amdgcn_s_barrier();
        bf16x8 af[4], bfr[4];
        load_frags(As[t&1], Bs[t&1], wr, wc, lrow, cs, af, bfr);
        if (t < NT-2) {
            asm volatile("s_waitcnt lgkmcnt(0)" ::: "memory");
            __builtin_amdgcn_s_barrier();
            stage_tile(A, Bt, K, m0, n0, (t+2) << 5, As[t&1], Bs[t&1]);
        }
        __builtin_amdgcn_sched_barrier(0);
        do_mfma(af, bfr, acc);
    }
    asm volatile("s_waitcnt vmcnt(0)" ::: "memory");
    __builtin_amdgcn_s_barrier();
    bf16x8 af[4], bfr[4];
    load_frags(As[(NT-1)&1], Bs[(NT-1)&1], wr, wc, lrow, cs, af, bfr);
    do_mfma(af, bfr, acc);
}

// Fused GEMM A: xb @ [w_pt1 | w_wg | w_mag | w_q1 | w_mix], N=7168, K=1024.
// 1D grid 1792; XCD k owns m-tiles [4k,4k+4) (A L2-resident), streams n.
__global__ __launch_bounds__(256,4) void mgemmA_k(
    const ushort* __restrict__ xb, const ushort* __restrict__ Wt,
    const float* __restrict__ b_pt1, const float* __restrict__ b_wg,
    const float* __restrict__ b_mag, const float* __restrict__ b_q1,
    const float* __restrict__ b_mix, const float* __restrict__ gtemp,
    ushort* __restrict__ H1b, ushort* __restrict__ wgb, ushort* __restrict__ magb,
    ushort* __restrict__ Hqb, ushort* __restrict__ mixb)
{
    __shared__ ushort As[2][4096], Bs[2][4096];
    int bid = blockIdx.x;
    int xcd = bid & 7, local = bid >> 3;          // local in [0,224)
    int m0 = (xcd*4 + (local & 3)) * 128;
    int n0 = (local >> 2) * 128;                  // 56 n-panels
    f32x4 acc[4][4] = {};
    mgemm_core(xb, Wt, 1024, m0, n0, As, Bs, acc);
    int lane = threadIdx.x & 63, wave = threadIdx.x >> 6;
    int wr = wave >> 1, wc = wave & 1;
    int rng = n0 >> 10;           // 0,1:pt1  2:wg  3:mag  4:q1  5,6:mix
    float gt = gtemp[0];
    #pragma unroll
    for (int i = 0; i < 4; i++) {
        int mb = m0 + wr*64 + i*16 + (lane>>4)*4;
        #pragma unroll
        for (int j = 0; j < 4; j++) {
            int n = n0 + wc*64 + j*16 + (lane&15);
            #pragma unroll
            for (int r = 0; r < 4; r++) {
                int m = mb + r;
                float v = acc[i][j][r];
                if (rng < 2) {
                    H1b[(size_t)m*D2 + n] = f2bf(geluf(v + b_pt1[n]));
                } else if (rng == 2) {
                    wgb[(size_t)m*DD + n-2048] = f2bf(sigmf((v + b_wg[n-2048])*gt));
                } else if (rng == 3) {
                    magb[(size_t)m*DD + n-3072] = f2bf(sigmf(v + b_mag[n-3072])*5.0f);
                } else if (rng == 4) {
                    Hqb[(size_t)m*DD + n-4096] = f2bf(geluf(v + b_q1[n-4096]));
                } else {
                    mixb[(size_t)m*D2 + n-5120] = f2bf(sigmf(v + b_mix[n-5120]));
                }
            }
        }
    }
}

// z=0: pd = bf16((H1 @ w_pt2 + b_pt2) * |iscale|) (K=2048)
// z=1: qadj = bf16(Hq @ w_q2 + b_q2)              (K=1024)
__global__ __launch_bounds__(256,4) void mgemmBC_k(
    const ushort* __restrict__ H1b, const ushort* __restrict__ wt_pt2,
    const ushort* __restrict__ Hqb, const ushort* __restrict__ wt_q2,
    const float* __restrict__ b_pt2, const float* __restrict__ b_q2,
    const float* __restrict__ iscale,
    ushort* __restrict__ pdb, ushort* __restrict__ qadjb)
{
    __shared__ ushort As[2][4096], Bs[2][4096];
    int bid = blockIdx.x;
    int xcd = bid & 7, local = bid >> 3;          // [0,64)
    int m0 = (xcd*4 + (local & 3)) * 128;
    int rest = local >> 2;                        // [0,16)
    int z = rest >> 3;
    int n0 = (rest & 7) * 128;
    const ushort* A  = z ? Hqb   : H1b;
    const ushort* Bt = z ? wt_q2 : wt_pt2;
    const float* bias = z ? b_q2 : b_pt2;
    int K = z ? 1024 : 2048;
    ushort* outp = z ? qadjb : pdb;
    f32x4 acc[4][4] = {};
    mgemm_core(A, Bt, K, m0, n0, As, Bs, acc);
    int lane = threadIdx.x & 63, wave = threadIdx.x >> 6;
    int wr = wave >> 1, wc = wave & 1;
    #pragma unroll
    for (int i = 0; i < 4; i++) {
        int mb = m0 + wr*64 + i*16 + (lane>>4)*4;
        #pragma unroll
        for (int j = 0; j < 4; j++) {
            int n = n0 + wc*64 + j*16 + (lane&15);
            float bv = bias[n];
            float sc = z ? 1.0f : fabsf(iscale[n]);
            #pragma unroll
            for (int r = 0; r < 4; r++) {
                float v = acc[i][j][r] + bv;
                outp[(size_t)(mb+r)*DD + n] = f2bf(z ? v : v*sc);
            }
        }
    }
}

// head GEMMs; 1D grid 256
template<int ACT, bool RESID, bool OUTBF16>
__global__ __launch_bounds__(256,4) void mgemm_k(
    const ushort* __restrict__ A, const ushort* __restrict__ Bt,
    const float* __restrict__ bias, const float* __restrict__ resid,
    void* __restrict__ Cout, int N, int K)
{
    __shared__ ushort As[2][4096], Bs[2][4096];
    int bid = blockIdx.x;
    int xcd = bid & 7, local = bid >> 3;          // [0,32)
    int m0 = (xcd*4 + (local & 3)) * 128;
    int n0 = (local >> 2) * 128;                  // 8 n-panels
    f32x4 acc[4][4] = {};
    mgemm_core(A, Bt, K, m0, n0, As, Bs, acc);
    int lane = threadIdx.x & 63, wave = threadIdx.x >> 6;
    int wr = wave >> 1, wc = wave & 1;
    #pragma unroll
    for (int i = 0; i < 4; i++) {
        int mb = m0 + wr*64 + i*16 + (lane>>4)*4;
        #pragma unroll
        for (int j = 0; j < 4; j++) {
            int n = n0 + wc*64 + j*16 + (lane&15);
            float bv = bias[n];
            #pragma unroll
            for (int r = 0; r < 4; r++) {
                size_t idx = (size_t)(mb + r)*N + n;
                float v = acc[i][j][r] + bv;
                if (ACT==1) v = geluf(v);
                if (RESID) v += resid[idx];
                if (OUTBF16) ((ushort*)Cout)[idx] = f2bf(v);
                else         ((float*)Cout)[idx]  = v;
            }
        }
    }
}

// ---------------- conversions ----------------
__global__ __launch_bounds__(256) void cvt_bf16_k(const float* __restrict__ in, ushort* __restrict__ outp){
    size_t i = ((size_t)blockIdx.x*256 + threadIdx.x)*8;
    float4 a = *(const float4*)(in + i);
    float4 b = *(const float4*)(in + i + 4);
    ushort t[8];
    t[0]=f2bf(a.x); t[1]=f2bf(a.y); t[2]=f2bf(a.z); t[3]=f2bf(a.w);
    t[4]=f2bf(b.x); t[5]=f2bf(b.y); t[6]=f2bf(b.z); t[7]=f2bf(b.w);
    *(int4*)(outp + i) = *(const int4*)t;
}

__device__ __forceinline__ void tcvt_body(const float* W, ushort* Wt, int K, int N){
    __shared__ float tile[32][33];
    int n0 = blockIdx.x*32, k0 = blockIdx.y*32;
    int tx = threadIdx.x & 7, ty = threadIdx.x >> 3;
    float4 v = *(const float4*)(W + (size_t)(k0+ty)*N + n0 + tx*4);
    tile[ty][tx*4+0]=v.x; tile[ty][tx*4+1]=v.y; tile[ty][tx*4+2]=v.z; tile[ty][tx*4+3]=v.w;
    __syncthreads();
    ushort t[4];
    #pragma unroll
    for (int i=0;i<4;i++) t[i] = f2bf(tile[tx*4+i][ty]);
    *(uint2*)(Wt + (size_t)(n0+ty)*K + k0 + tx*4) = *(const uint2*)t;
}

__global__ __launch_bounds__(256) void tcvt_k(const float* __restrict__ W, ushort* __restrict__ Wt, int K, int N){
    tcvt_body(W, Wt, K, N);
}
__global__ __launch_bounds__(256) void tcvt2_k(const float* __restrict__ w0, ushort* __restrict__ o0,
                                               const float* __restrict__ w1, ushort* __restrict__ o1){
    tcvt_body(blockIdx.z ? w1 : w0, blockIdx.z ? o1 : o0, 1024, 2048);
}
__global__ __launch_bounds__(256) void tcvt6_k(
    const float* __restrict__ w0, ushort* __restrict__ o0,
    const float* __restrict__ w1, ushort* __restrict__ o1,
    const float* __restrict__ w2, ushort* __restrict__ o2,
    const float* __restrict__ w3, ushort* __restrict__ o3,
    const float* __restrict__ w4, ushort* __restrict__ o4,
    const float* __restrict__ w5, ushort* __restrict__ o5)
{
    const float* W; ushort* Wt;
    switch(blockIdx.z){
        case 0: W=w0; Wt=o0; break;
        case 1: W=w1; Wt=o1; break;
        case 2: W=w2; Wt=o2; break;
        case 3: W=w3; Wt=o3; break;
        case 4: W=w4; Wt=o4; break;
        default: W=w5; Wt=o5; break;
    }
    tcvt_body(W, Wt, 1024, 1024);
}

// ---------------- scan complex (recompute-on-the-fly, 2 d-cols/thread) ----
__global__ __launch_bounds__(256) void passA_k(
    const ushort* __restrict__ pdb, float* __restrict__ csum)
{
    int d0 = (blockIdx.x*256 + threadIdx.x)*2;
    int c = blockIdx.y, b = blockIdx.z;
    const ushort* p = pdb + ((size_t)b*SS + (size_t)c*CL2)*DD + d0;
    float s0 = 0.f, s1 = 0.f;
    for (int i = 0; i < CL2; i++){
        ushort2 v = *(const ushort2*)(p + (size_t)i*DD);
        s0 += bf2f(v.x); s1 += bf2f(v.y);
    }
    *(float2*)(csum + ((size_t)b*NC2 + c)*DD + d0) = make_float2(s0, s1);
}

__global__ void scan2_k(float* __restrict__ csum, int nchains){
    int idx = blockIdx.x*256 + threadIdx.x;
    if (idx >= nchains) return;
    int xg = idx / DD, d = idx % DD;
    float* p = csum + (size_t)xg*NC2*DD + d;
    float run = 0.f;
    for (int c = 0; c < NC2; c++){ float t = p[(size_t)c*DD]; p[(size_t)c*DD] = run; run += t; }
}

__global__ __launch_bounds__(256) void passB_k(
    const ushort* __restrict__ pdb, const ushort* __restrict__ wgb,
    const ushort* __restrict__ magb, const ushort* __restrict__ xb,
    const float* __restrict__ csum_phi, float* __restrict__ csum_tri)
{
    int d0 = (blockIdx.x*256 + threadIdx.x)*2;
    int c = blockIdx.y, b = blockIdx.z;
    size_t off = ((size_t)b*SS + (size_t)c*CL2)*DD + d0;
    float2 phv = *(const float2*)(csum_phi + ((size_t)b*NC2 + c)*DD + d0);
    float ph0 = phv.x, ph1 = phv.y;
    float a0=0.f, a1=0.f, b0=0.f, b1=0.f, c0=0.f, c1=0.f;
    for (int i = 0; i < CL2; i++){
        size_t o = off + (size_t)i*DD;
        ushort2 pdv = *(const ushort2*)(pdb + o);
        ushort2 wgv = *(const ushort2*)(wgb + o);
        ushort2 mgv = *(const ushort2*)(magb + o);
        ushort2 xv  = *(const ushort2*)(xb + o);
        ph0 += bf2f(pdv.x); ph1 += bf2f(pdv.y);
        float w0 = bf2f(wgv.x), w1 = bf2f(wgv.y);
        float m0 = bf2f(mgv.x), m1 = bf2f(mgv.y);
        float ct0 = w0*bf2f(xv.x)*m0, ct1 = w1*bf2f(xv.y)*m1;
        float sp0, cp0, sp1, cp1;
        sincosf(ph0, &sp0, &cp0); sincosf(ph1, &sp1, &cp1);
        a0 += ct0*cp0; a1 += ct1*cp1;
        b0 += ct0*sp0; b1 += ct1*sp1;
        c0 += fmaf(w0, m0, 1e-8f); c1 += fmaf(w1, m1, 1e-8f);
    }
    size_t cs = ((size_t)b*NC2 + c)*DD + d0;
    size_t G = (size_t)BB*NC2*DD;
    *(float2*)(csum_tri + cs)     = make_float2(a0, a1);
    *(float2*)(csum_tri + G+cs)   = make_float2(b0, b1);
    *(float2*)(csum_tri + 2*G+cs) = make_float2(c0, c1);
}

__global__ __launch_bounds__(256) void passC_k(
    const ushort* __restrict__ pdb, const ushort* __restrict__ wgb,
    const ushort* __restrict__ magb, const ushort* __restrict__ xb,
    const ushort* __restrict__ qadjb, const ushort* __restrict__ mixb,
    const float* __restrict__ csum_phi, const float* __restrict__ csum_tri,
    ushort* __restrict__ ret)
{
    int d0 = (blockIdx.x*256 + threadIdx.x)*2;
    int c = blockIdx.y, b = blockIdx.z;
    size_t off = ((size_t)b*SS + (size_t)c*CL2)*DD + d0;
    size_t cs = ((size_t)b*NC2 + c)*DD + d0;
    size_t G = (size_t)BB*NC2*DD;
    float2 phv = *(const float2*)(csum_phi + cs);
    float2 r0v = *(const float2*)(csum_tri + cs);
    float2 r1v = *(const float2*)(csum_tri + G+cs);
    float2 r2v = *(const float2*)(csum_tri + 2*G+cs);
    float ph0 = phv.x, ph1 = phv.y;
    float p0 = r0v.x, p1 = r0v.y, q0 = r1v.x, q1 = r1v.y, s0 = r2v.x, s1 = r2v.y;
    size_t row0 = (size_t)b*SS + (size_t)c*CL2;
    for (int i = 0; i < CL2; i++){
        size_t o = off + (size_t)i*DD;
        ushort2 pdv = *(const ushort2*)(pdb + o);
        ushort2 wgv = *(const ushort2*)(wgb + o);
        ushort2 mgv = *(const ushort2*)(magb + o);
        ushort2 xv  = *(const ushort2*)(xb + o);
        ushort2 qav = *(const ushort2*)(qadjb + o);
        size_t mb2 = (row0 + i)*D2 + d0;
        ushort2 mrv = *(const ushort2*)(mixb + mb2);
        ushort2 miv = *(const ushort2*)(mixb + mb2 + DD);
        ph0 += bf2f(pdv.x); ph1 += bf2f(pdv.y);
        float w0 = bf2f(wgv.x), w1 = bf2f(wgv.y);
        float m0 = bf2f(mgv.x), m1 = bf2f(mgv.y);
        float ct0 = w0*bf2f(xv.x)*m0, ct1 = w1*bf2f(xv.y)*m1;
        float sp0, cp0, sp1, cp1;
        sincosf(ph0, &sp0, &cp0); sincosf(ph1, &sp1, &cp1);
        p0 += ct0*cp0; p1 += ct1*cp1;
        q0 += ct0*sp0; q1 += ct1*sp1;
        s0 += fmaf(w0, m0, 1e-8f); s1 += fmaf(w1, m1, 1e-8f);
        float inv0 = rsqrtf(s0), inv1 = rsqrtf(s1);
        float mr0 = p0*inv0, mi0 = q0*inv0;
        float mr1 = p1*inv1, mi1 = q1*inv1;
        float sq0, cq0, sq1, cq1;
        sincosf(ph0 + bf2f(qav.x), &sq0, &cq0);
        sincosf(ph1 + bf2f(qav.y), &sq1, &cq1);
        float rr0 = mr0*cq0 + mi0*sq0, ri0 = mi0*cq0 - mr0*sq0;
        float rr1 = mr1*cq1 + mi1*sq1, ri1 = mi1*cq1 - mr1*sq1;
        ushort2 rv;
        rv.x = f2bf(bf2f(mrv.x)*rr0 + bf2f(miv.x)*ri0);
        rv.y = f2bf(bf2f(mrv.y)*rr1 + bf2f(miv.y)*ri1);
        *(ushort2*)(ret + o) = rv;
    }
}

// LayerNorm over d per row; bf16 in/out, ushort4 vectorized
__global__ __launch_bounds__(256) void ln_k(
    const ushort* __restrict__ ret, const float* __restrict__ ln_g,
    const float* __restrict__ ln_b, ushort* __restrict__ outp)
{
    int row = blockIdx.x;
    size_t base = (size_t)row*DD;
    int d0 = threadIdx.x*4;
    ushort4 rv = *(const ushort4*)(ret + base + d0);
    float v0 = bf2f(rv.x), v1 = bf2f(rv.y), v2 = bf2f(rv.z), v3 = bf2f(rv.w);
    float sum = v0+v1+v2+v3;
    float sumsq = v0*v0 + v1*v1 + v2*v2 + v3*v3;
    #pragma unroll
    for (int off=32; off; off>>=1){
        sum   += __shfl_down(sum,off);
        sumsq += __shfl_down(sumsq,off);
    }
    __shared__ float red[8];
    int lane = threadIdx.x & 63, wid = threadIdx.x >> 6;
    if (lane==0){ red[wid]=sum; red[4+wid]=sumsq; }
    __syncthreads();
    sum   = red[0]+red[1]+red[2]+red[3];
    sumsq = red[4]+red[5]+red[6]+red[7];
    float mu  = sum * (1.0f/DD);
    float var = sumsq*(1.0f/DD) - mu*mu;
    float rstd = rsqrtf(var + 1e-5f);
    float4 g = *(const float4*)(ln_g + d0);
    float4 bb = *(const float4*)(ln_b + d0);
    ushort4 ov;
    ov.x = f2bf((v0-mu)*rstd*g.x + bb.x);
    ov.y = f2bf((v1-mu)*rstd*g.y + bb.y);
    ov.z = f2bf((v2-mu)*rstd*g.z + bb.z);
    ov.w = f2bf((v3-mu)*rstd*g.w + bb.w);
    *(ushort4*)(outp + base + d0) = ov;
}

extern "C" void kernel_launch(void* const* d_in, const int* in_sizes, int n_in,
                              void* d_out, int out_size, void* d_ws, size_t ws_size,
                              hipStream_t stream)
{
    const float* x     = (const float*)d_in[0];
    const float* w_pt1 = (const float*)d_in[1];
    const float* b_pt1 = (const float*)d_in[2];
    const float* w_pt2 = (const float*)d_in[3];
    const float* b_pt2 = (const float*)d_in[4];
    const float* iscale= (const float*)d_in[5];
    const float* w_wg  = (const float*)d_in[6];
    const float* b_wg  = (const float*)d_in[7];
    const float* gtemp = (const float*)d_in[8];
    const float* w_mag = (const float*)d_in[9];
    const float* b_mag = (const float*)d_in[10];
    const float* w_q1  = (const float*)d_in[11];
    const float* b_q1  = (const float*)d_in[12];
    const float* w_q2  = (const float*)d_in[13];
    const float* b_q2  = (const float*)d_in[14];
    const float* w_mix = (const float*)d_in[15];
    const float* b_mix = (const float*)d_in[16];
    const float* ln_g  = (const float*)d_in[17];
    const float* ln_b  = (const float*)d_in[18];
    const float* w_o1  = (const float*)d_in[19];
    const float* b_o1  = (const float*)d_in[20];
    const float* w_o2  = (const float*)d_in[21];
    const float* b_o2  = (const float*)d_in[22];
    float* out = (float*)d_out;

    const size_t SZ = (size_t)MTOT*DD;     // 4M elems
    ushort* u = (ushort*)d_ws;
    ushort* xb    = u;                 u += SZ;        // bf16 x
    ushort* H1b   = u;                 u += 2*SZ;      // [4096][2048]
    ushort* ret   = H1b;                                // alias (H1b dead after BC)
    ushort* Hqb   = u;                 u += SZ;
    ushort* lnb   = Hqb;                                // alias (Hqb dead after BC)
    ushort* wgb   = u;                 u += SZ;
    ushort* magb  = u;                 u += SZ;
    ushort* mixb  = u;                 u += 2*SZ;      // [4096][2048]
    ushort* Hob   = u;                 u += SZ;
    ushort* pdb   = u;                 u += SZ;        // bf16
    ushort* qadjb = u;                 u += SZ;        // bf16
    ushort* Wt_all= u;                 u += (size_t)7168*1024;
    ushort* wt_pt2= u;                 u += (size_t)1024*2048;
    ushort* wt_q2 = u;                 u += (size_t)1024*1024;
    ushort* wt_o1 = u;                 u += (size_t)1024*1024;
    ushort* wt_o2 = u;                 u += (size_t)1024*1024;
    float* csum_phi = (float*)u;                       // BB*NC2*DD
    float* csum_tri = csum_phi + (size_t)BB*NC2*DD;    // 3x

    dim3 blk(256);
    // conversions
    cvt_bf16_k<<<dim3(SZ/2048), blk, 0, stream>>>(x, xb);
    tcvt2_k<<<dim3(64, 32, 2), blk, 0, stream>>>(w_pt1, Wt_all, w_mix, Wt_all + (size_t)5120*1024);
    tcvt6_k<<<dim3(32, 32, 6), blk, 0, stream>>>(
        w_wg,  Wt_all + (size_t)2048*1024,
        w_mag, Wt_all + (size_t)3072*1024,
        w_q1,  Wt_all + (size_t)4096*1024,
        w_q2,  wt_q2,  w_o1, wt_o1,  w_o2, wt_o2);
    tcvt_k<<<dim3(32, 64), blk, 0, stream>>>(w_pt2, wt_pt2, 2048, 1024);
    // fused GEMM A (1792 blocks, XCD-chunked, r6 128^2 core)
    mgemmA_k<<<dim3(1792), blk, 0, stream>>>(xb, Wt_all, b_pt1, b_wg, b_mag, b_q1, b_mix,
                                             gtemp, H1b, wgb, magb, Hqb, mixb);
    // GEMM B/C (512 blocks)
    mgemmBC_k<<<dim3(512), blk, 0, stream>>>(H1b, wt_pt2, Hqb, wt_q2, b_pt2, b_q2,
                                             iscale, pdb, qadjb);
    // scan complex
    passA_k<<<dim3(DD/512, NC2, BB), blk, 0, stream>>>(pdb, csum_phi);
    scan2_k<<<dim3((BB*DD+255)/256), blk, 0, stream>>>(csum_phi, BB*DD);
    passB_k<<<dim3(DD/512, NC2, BB), blk, 0, stream>>>(pdb, wgb, magb, xb, csum_phi, csum_tri);
    scan2_k<<<dim3((3*BB*DD+255)/256), blk, 0, stream>>>(csum_tri, 3*BB*DD);
    passC_k<<<dim3(DD/512, NC2, BB), blk, 0, stream>>>(pdb, wgb, magb, xb, qadjb, mixb,
                                                       csum_phi, csum_tri, ret);
    ln_k<<<dim3(MTOT), blk, 0, stream>>>(ret, ln_g, ln_b, lnb);
    // output head (256 blocks each)
    mgemm_k<1,false,true><<<dim3(256), blk, 0, stream>>>(lnb, wt_o1, b_o1, nullptr, Hob, DD, DD);
    mgemm_k<0,true,false><<<dim3(256), blk, 0, stream>>>(Hob, wt_o2, b_o2, x, out, DD, DD);
}

// Round 11
// 240.036 us; speedup vs baseline: 1.6168x; 1.0563x over previous
//
#include <hip/hip_runtime.h>
#include <hip/hip_bf16.h>

#define MTOT 4096   // B*S
#define DD   1024
#define D2   2048
#define SS   2048
#define BB   2
#define NC2  128
#define CL2  (SS/NC2)   // 16

typedef __attribute__((ext_vector_type(8))) short bf16x8;
typedef __attribute__((ext_vector_type(4))) float f32x4;

__device__ __forceinline__ float sigmf(float v){
    return 1.0f/(1.0f+__expf(-v));
}
__device__ __forceinline__ float geluf(float v){
    float u = 0.7978845608f*v*(1.0f + 0.044715f*v*v);
    float e = __expf(2.0f*u);
    float t = 1.0f - 2.0f/(e + 1.0f);
    return 0.5f*v*(1.0f + t);
}
__device__ __forceinline__ ushort f2bf(float f){
    unsigned u = __float_as_uint(f);
    unsigned r = (u + 0x7FFF + ((u>>16)&1)) >> 16;
    return (ushort)r;
}
__device__ __forceinline__ float bf2f(ushort u){
    return __uint_as_float(((unsigned)u)<<16);
}

// ================= 128x128 core (round-6, proven) ======
// BK=32, depth-2 counted-vmcnt pipeline, 8-elem XOR swizzle (2-way free),
// both-sides rule: linear LDS dest + inverse-swizzled global src + swizzled read.
__device__ __forceinline__ void stage_tile(
    const ushort* __restrict__ A, const ushort* __restrict__ Bt, int K,
    int m0, int n0, int k0, ushort* As, ushort* Bs)
{
    int tid = threadIdx.x;
    #pragma unroll
    for (int i = 0; i < 2; i++) {
        int e = (i*256 + tid) * 8;          // elem in [128][32] tile (linear LDS)
        int r = e >> 5;
        int s = (e >> 3) & 3;
        int c = ((s ^ ((r >> 1) & 3)) << 3);   // inverse-swizzled source col
        __builtin_amdgcn_global_load_lds(
            (const __attribute__((address_space(1))) void*)(A + (size_t)(m0 + r)*K + k0 + c),
            (__attribute__((address_space(3))) void*)(As + e), 16, 0, 0);
        __builtin_amdgcn_global_load_lds(
            (const __attribute__((address_space(1))) void*)(Bt + (size_t)(n0 + r)*K + k0 + c),
            (__attribute__((address_space(3))) void*)(Bs + e), 16, 0, 0);
    }
}

__device__ __forceinline__ void load_frags(
    const ushort* As, const ushort* Bs, int wr, int wc, int lrow, int cs,
    bf16x8 (&af)[4], bf16x8 (&bfr)[4])
{
    #pragma unroll
    for (int i = 0; i < 4; i++) {
        int ra = wr*64 + i*16 + lrow;
        int rb = wc*64 + i*16 + lrow;
        af[i]  = *(const bf16x8*)(As + ra*32 + ((cs ^ ((ra>>1)&3))<<3));
        bfr[i] = *(const bf16x8*)(Bs + rb*32 + ((cs ^ ((rb>>1)&3))<<3));
    }
}

__device__ __forceinline__ void do_mfma(
    const bf16x8 (&af)[4], const bf16x8 (&bfr)[4], f32x4 (&acc)[4][4])
{
    __builtin_amdgcn_s_setprio(1);
    #pragma unroll
    for (int i = 0; i < 4; i++)
        #pragma unroll
        for (int j = 0; j < 4; j++)
            acc[i][j] = __builtin_amdgcn_mfma_f32_16x16x32_bf16(af[i], bfr[j], acc[i][j], 0, 0, 0);
    __builtin_amdgcn_s_setprio(0);
}

__device__ __forceinline__ void mgemm_core(
    const ushort* __restrict__ A, const ushort* __restrict__ Bt, int K,
    int m0, int n0, ushort (&As)[2][4096], ushort (&Bs)[2][4096], f32x4 (&acc)[4][4])
{
    int lane = threadIdx.x & 63, wave = threadIdx.x >> 6;
    int wr = wave >> 1, wc = wave & 1;
    int lrow = lane & 15, cs = lane >> 4;
    int NT = K >> 5;
    stage_tile(A, Bt, K, m0, n0, 0,  As[0], Bs[0]);
    stage_tile(A, Bt, K, m0, n0, 32, As[1], Bs[1]);
    for (int t = 0; t < NT-1; ++t) {
        asm volatile("s_waitcnt vmcnt(4)" ::: "memory");
        __builtin_amdgcn_s_barrier();
        bf16x8 af[4], bfr[4];
        load_frags(As[t&1], Bs[t&1], wr, wc, lrow, cs, af, bfr);
        if (t < NT-2) {
            asm volatile("s_waitcnt lgkmcnt(0)" ::: "memory");
            __builtin_amdgcn_s_barrier();
            stage_tile(A, Bt, K, m0, n0, (t+2) << 5, As[t&1], Bs[t&1]);
        }
        __builtin_amdgcn_sched_barrier(0);
        do_mfma(af, bfr, acc);
    }
    asm volatile("s_waitcnt vmcnt(0)" ::: "memory");
    __builtin_amdgcn_s_barrier();
    bf16x8 af[4], bfr[4];
    load_frags(As[(NT-1)&1], Bs[(NT-1)&1], wr, wc, lrow, cs, af, bfr);
    do_mfma(af, bfr, acc);
}

// Fused GEMM A: xb @ [w_pt1 | w_wg | w_mag | w_q1 | w_mix], N=7168, K=1024.
// 1D grid 1792; XCD k owns m-tiles [4k,4k+4) (A L2-resident), streams n.
__global__ __launch_bounds__(256,4) void mgemmA_k(
    const ushort* __restrict__ xb, const ushort* __restrict__ Wt,
    const float* __restrict__ b_pt1, const float* __restrict__ b_wg,
    const float* __restrict__ b_mag, const float* __restrict__ b_q1,
    const float* __restrict__ b_mix, const float* __restrict__ gtemp,
    ushort* __restrict__ H1b, ushort* __restrict__ wgb, ushort* __restrict__ magb,
    ushort* __restrict__ Hqb, ushort* __restrict__ mixb)
{
    __shared__ ushort As[2][4096], Bs[2][4096];
    int bid = blockIdx.x;
    int xcd = bid & 7, local = bid >> 3;          // local in [0,224)
    int m0 = (xcd*4 + (local & 3)) * 128;
    int n0 = (local >> 2) * 128;                  // 56 n-panels
    f32x4 acc[4][4] = {};
    mgemm_core(xb, Wt, 1024, m0, n0, As, Bs, acc);
    int lane = threadIdx.x & 63, wave = threadIdx.x >> 6;
    int wr = wave >> 1, wc = wave & 1;
    int rng = n0 >> 10;           // 0,1:pt1  2:wg  3:mag  4:q1  5,6:mix
    float gt = gtemp[0];
    #pragma unroll
    for (int i = 0; i < 4; i++) {
        int mb = m0 + wr*64 + i*16 + (lane>>4)*4;
        #pragma unroll
        for (int j = 0; j < 4; j++) {
            int n = n0 + wc*64 + j*16 + (lane&15);
            #pragma unroll
            for (int r = 0; r < 4; r++) {
                int m = mb + r;
                float v = acc[i][j][r];
                if (rng < 2) {
                    H1b[(size_t)m*D2 + n] = f2bf(geluf(v + b_pt1[n]));
                } else if (rng == 2) {
                    wgb[(size_t)m*DD + n-2048] = f2bf(sigmf((v + b_wg[n-2048])*gt));
                } else if (rng == 3) {
                    magb[(size_t)m*DD + n-3072] = f2bf(sigmf(v + b_mag[n-3072])*5.0f);
                } else if (rng == 4) {
                    Hqb[(size_t)m*DD + n-4096] = f2bf(geluf(v + b_q1[n-4096]));
                } else {
                    mixb[(size_t)m*D2 + n-5120] = f2bf(sigmf(v + b_mix[n-5120]));
                }
            }
        }
    }
}

// z=0: pd = bf16((H1 @ w_pt2 + b_pt2) * |iscale|) (K=2048) + fused phi chunk sums
// z=1: qadj = bf16(Hq @ w_q2 + b_q2)              (K=1024)
__global__ __launch_bounds__(256,4) void mgemmBC_k(
    const ushort* __restrict__ H1b, const ushort* __restrict__ wt_pt2,
    const ushort* __restrict__ Hqb, const ushort* __restrict__ wt_q2,
    const float* __restrict__ b_pt2, const float* __restrict__ b_q2,
    const float* __restrict__ iscale,
    ushort* __restrict__ pdb, ushort* __restrict__ qadjb,
    float* __restrict__ csum_phi)
{
    __shared__ ushort As[2][4096], Bs[2][4096];
    int bid = blockIdx.x;
    int xcd = bid & 7, local = bid >> 3;          // [0,64)
    int m0 = (xcd*4 + (local & 3)) * 128;
    int rest = local >> 2;                        // [0,16)
    int z = rest >> 3;
    int n0 = (rest & 7) * 128;
    const ushort* A  = z ? Hqb   : H1b;
    const ushort* Bt = z ? wt_q2 : wt_pt2;
    const float* bias = z ? b_q2 : b_pt2;
    int K = z ? 1024 : 2048;
    ushort* outp = z ? qadjb : pdb;
    f32x4 acc[4][4] = {};
    mgemm_core(A, Bt, K, m0, n0, As, Bs, acc);
    int lane = threadIdx.x & 63, wave = threadIdx.x >> 6;
    int wr = wave >> 1, wc = wave & 1;
    float csum_ij[4][4];
    #pragma unroll
    for (int i = 0; i < 4; i++) {
        int mb = m0 + wr*64 + i*16 + (lane>>4)*4;
        #pragma unroll
        for (int j = 0; j < 4; j++) {
            int n = n0 + wc*64 + j*16 + (lane&15);
            float bv = bias[n];
            float sc = z ? 1.0f : fabsf(iscale[n]);
            float s = 0.f;
            #pragma unroll
            for (int r = 0; r < 4; r++) {
                float v = acc[i][j][r] + bv;
                ushort bfv = f2bf(z ? v : v*sc);
                outp[(size_t)(mb+r)*DD + n] = bfv;
                s += bf2f(bfv);
            }
            csum_ij[i][j] = s;
        }
    }
    if (z == 0) {
        // fused passA: chunk (16 rows) sums of the stored bf16 pd values.
        // (wr,i) covers exactly chunk m0/16 + wr*4 + i; reduce over lane>>4.
        int b = m0 >> 11;
        int c0 = (m0 & 2047) >> 4;
        #pragma unroll
        for (int i = 0; i < 4; i++) {
            int c = c0 + wr*4 + i;
            #pragma unroll
            for (int j = 0; j < 4; j++) {
                float s = csum_ij[i][j];
                s += __shfl_xor(s, 16);
                s += __shfl_xor(s, 32);
                if ((lane >> 4) == 0) {
                    int n = n0 + wc*64 + j*16 + (lane&15);
                    csum_phi[((size_t)b*NC2 + c)*DD + n] = s;
                }
            }
        }
    }
}

// head GEMMs; 1D grid 256
template<int ACT, bool RESID, bool OUTBF16>
__global__ __launch_bounds__(256,4) void mgemm_k(
    const ushort* __restrict__ A, const ushort* __restrict__ Bt,
    const float* __restrict__ bias, const float* __restrict__ resid,
    void* __restrict__ Cout, int N, int K)
{
    __shared__ ushort As[2][4096], Bs[2][4096];
    int bid = blockIdx.x;
    int xcd = bid & 7, local = bid >> 3;          // [0,32)
    int m0 = (xcd*4 + (local & 3)) * 128;
    int n0 = (local >> 2) * 128;                  // 8 n-panels
    f32x4 acc[4][4] = {};
    mgemm_core(A, Bt, K, m0, n0, As, Bs, acc);
    int lane = threadIdx.x & 63, wave = threadIdx.x >> 6;
    int wr = wave >> 1, wc = wave & 1;
    #pragma unroll
    for (int i = 0; i < 4; i++) {
        int mb = m0 + wr*64 + i*16 + (lane>>4)*4;
        #pragma unroll
        for (int j = 0; j < 4; j++) {
            int n = n0 + wc*64 + j*16 + (lane&15);
            float bv = bias[n];
            #pragma unroll
            for (int r = 0; r < 4; r++) {
                size_t idx = (size_t)(mb + r)*N + n;
                float v = acc[i][j][r] + bv;
                if (ACT==1) v = geluf(v);
                if (RESID) v += resid[idx];
                if (OUTBF16) ((ushort*)Cout)[idx] = f2bf(v);
                else         ((float*)Cout)[idx]  = v;
            }
        }
    }
}

// ---------------- conversions ----------------
__global__ __launch_bounds__(256) void cvt_bf16_k(const float* __restrict__ in, ushort* __restrict__ outp){
    size_t i = ((size_t)blockIdx.x*256 + threadIdx.x)*8;
    float4 a = *(const float4*)(in + i);
    float4 b = *(const float4*)(in + i + 4);
    ushort t[8];
    t[0]=f2bf(a.x); t[1]=f2bf(a.y); t[2]=f2bf(a.z); t[3]=f2bf(a.w);
    t[4]=f2bf(b.x); t[5]=f2bf(b.y); t[6]=f2bf(b.z); t[7]=f2bf(b.w);
    *(int4*)(outp + i) = *(const int4*)t;
}

__device__ __forceinline__ void tcvt_body(const float* W, ushort* Wt, int K, int N, int n0, int k0){
    __shared__ float tile[32][33];
    int tx = threadIdx.x & 7, ty = threadIdx.x >> 3;
    float4 v = *(const float4*)(W + (size_t)(k0+ty)*N + n0 + tx*4);
    tile[ty][tx*4+0]=v.x; tile[ty][tx*4+1]=v.y; tile[ty][tx*4+2]=v.z; tile[ty][tx*4+3]=v.w;
    __syncthreads();
    ushort t[4];
    #pragma unroll
    for (int i=0;i<4;i++) t[i] = f2bf(tile[tx*4+i][ty]);
    *(uint2*)(Wt + (size_t)(n0+ty)*K + k0 + tx*4) = *(const uint2*)t;
}

// all 9 weight transposes in one dispatch; grid 12288
__global__ __launch_bounds__(256) void tcvt_all_k(
    const float* __restrict__ w_pt1, const float* __restrict__ w_mix,
    const float* __restrict__ w_wg,  const float* __restrict__ w_mag,
    const float* __restrict__ w_q1,  const float* __restrict__ w_q2,
    const float* __restrict__ w_o1,  const float* __restrict__ w_o2,
    const float* __restrict__ w_pt2,
    ushort* __restrict__ Wt_all, ushort* __restrict__ wt_q2,
    ushort* __restrict__ wt_o1,  ushort* __restrict__ wt_o2,
    ushort* __restrict__ wt_pt2)
{
    int bid = blockIdx.x;
    const float* W; ushort* Wt; int K, N, tile;
    if (bid < 2048)        { W=w_pt1; Wt=Wt_all;                      K=1024; N=2048; tile=bid; }
    else if (bid < 4096)   { W=w_mix; Wt=Wt_all+(size_t)5120*1024;    K=1024; N=2048; tile=bid-2048; }
    else if (bid < 5120)   { W=w_wg;  Wt=Wt_all+(size_t)2048*1024;    K=1024; N=1024; tile=bid-4096; }
    else if (bid < 6144)   { W=w_mag; Wt=Wt_all+(size_t)3072*1024;    K=1024; N=1024; tile=bid-5120; }
    else if (bid < 7168)   { W=w_q1;  Wt=Wt_all+(size_t)4096*1024;    K=1024; N=1024; tile=bid-6144; }
    else if (bid < 8192)   { W=w_q2;  Wt=wt_q2;                       K=1024; N=1024; tile=bid-7168; }
    else if (bid < 9216)   { W=w_o1;  Wt=wt_o1;                       K=1024; N=1024; tile=bid-8192; }
    else if (bid < 10240)  { W=w_o2;  Wt=wt_o2;                       K=1024; N=1024; tile=bid-9216; }
    else                   { W=w_pt2; Wt=wt_pt2;                      K=2048; N=1024; tile=bid-10240; }
    int nx = N >> 5;
    int n0 = (tile % nx) * 32, k0 = (tile / nx) * 32;
    tcvt_body(W, Wt, K, N, n0, k0);
}

// ---------------- scan complex (recompute-on-the-fly, 2 d-cols/thread) ----
__global__ void scan2_k(float* __restrict__ csum, int nchains){
    int idx = blockIdx.x*256 + threadIdx.x;
    if (idx >= nchains) return;
    int xg = idx / DD, d = idx % DD;
    float* p = csum + (size_t)xg*NC2*DD + d;
    float run = 0.f;
    for (int c = 0; c < NC2; c++){ float t = p[(size_t)c*DD]; p[(size_t)c*DD] = run; run += t; }
}

__global__ __launch_bounds__(256) void passB_k(
    const ushort* __restrict__ pdb, const ushort* __restrict__ wgb,
    const ushort* __restrict__ magb, const ushort* __restrict__ xb,
    const float* __restrict__ csum_phi, float* __restrict__ csum_tri)
{
    int d0 = (blockIdx.x*256 + threadIdx.x)*2;
    int c = blockIdx.y, b = blockIdx.z;
    size_t off = ((size_t)b*SS + (size_t)c*CL2)*DD + d0;
    float2 phv = *(const float2*)(csum_phi + ((size_t)b*NC2 + c)*DD + d0);
    float ph0 = phv.x, ph1 = phv.y;
    float a0=0.f, a1=0.f, b0=0.f, b1=0.f, c0=0.f, c1=0.f;
    for (int i = 0; i < CL2; i++){
        size_t o = off + (size_t)i*DD;
        ushort2 pdv = *(const ushort2*)(pdb + o);
        ushort2 wgv = *(const ushort2*)(wgb + o);
        ushort2 mgv = *(const ushort2*)(magb + o);
        ushort2 xv  = *(const ushort2*)(xb + o);
        ph0 += bf2f(pdv.x); ph1 += bf2f(pdv.y);
        float w0 = bf2f(wgv.x), w1 = bf2f(wgv.y);
        float m0 = bf2f(mgv.x), m1 = bf2f(mgv.y);
        float ct0 = w0*bf2f(xv.x)*m0, ct1 = w1*bf2f(xv.y)*m1;
        float sp0, cp0, sp1, cp1;
        sincosf(ph0, &sp0, &cp0); sincosf(ph1, &sp1, &cp1);
        a0 += ct0*cp0; a1 += ct1*cp1;
        b0 += ct0*sp0; b1 += ct1*sp1;
        c0 += fmaf(w0, m0, 1e-8f); c1 += fmaf(w1, m1, 1e-8f);
    }
    size_t cs = ((size_t)b*NC2 + c)*DD + d0;
    size_t G = (size_t)BB*NC2*DD;
    *(float2*)(csum_tri + cs)     = make_float2(a0, a1);
    *(float2*)(csum_tri + G+cs)   = make_float2(b0, b1);
    *(float2*)(csum_tri + 2*G+cs) = make_float2(c0, c1);
}

__global__ __launch_bounds__(256) void passC_k(
    const ushort* __restrict__ pdb, const ushort* __restrict__ wgb,
    const ushort* __restrict__ magb, const ushort* __restrict__ xb,
    const ushort* __restrict__ qadjb, const ushort* __restrict__ mixb,
    const float* __restrict__ csum_phi, const float* __restrict__ csum_tri,
    ushort* __restrict__ ret)
{
    int d0 = (blockIdx.x*256 + threadIdx.x)*2;
    int c = blockIdx.y, b = blockIdx.z;
    size_t off = ((size_t)b*SS + (size_t)c*CL2)*DD + d0;
    size_t cs = ((size_t)b*NC2 + c)*DD + d0;
    size_t G = (size_t)BB*NC2*DD;
    float2 phv = *(const float2*)(csum_phi + cs);
    float2 r0v = *(const float2*)(csum_tri + cs);
    float2 r1v = *(const float2*)(csum_tri + G+cs);
    float2 r2v = *(const float2*)(csum_tri + 2*G+cs);
    float ph0 = phv.x, ph1 = phv.y;
    float p0 = r0v.x, p1 = r0v.y, q0 = r1v.x, q1 = r1v.y, s0 = r2v.x, s1 = r2v.y;
    size_t row0 = (size_t)b*SS + (size_t)c*CL2;
    for (int i = 0; i < CL2; i++){
        size_t o = off + (size_t)i*DD;
        ushort2 pdv = *(const ushort2*)(pdb + o);
        ushort2 wgv = *(const ushort2*)(wgb + o);
        ushort2 mgv = *(const ushort2*)(magb + o);
        ushort2 xv  = *(const ushort2*)(xb + o);
        ushort2 qav = *(const ushort2*)(qadjb + o);
        size_t mb2 = (row0 + i)*D2 + d0;
        ushort2 mrv = *(const ushort2*)(mixb + mb2);
        ushort2 miv = *(const ushort2*)(mixb + mb2 + DD);
        ph0 += bf2f(pdv.x); ph1 += bf2f(pdv.y);
        float w0 = bf2f(wgv.x), w1 = bf2f(wgv.y);
        float m0 = bf2f(mgv.x), m1 = bf2f(mgv.y);
        float ct0 = w0*bf2f(xv.x)*m0, ct1 = w1*bf2f(xv.y)*m1;
        float sp0, cp0, sp1, cp1;
        sincosf(ph0, &sp0, &cp0); sincosf(ph1, &sp1, &cp1);
        p0 += ct0*cp0; p1 += ct1*cp1;
        q0 += ct0*sp0; q1 += ct1*sp1;
        s0 += fmaf(w0, m0, 1e-8f); s1 += fmaf(w1, m1, 1e-8f);
        float inv0 = rsqrtf(s0), inv1 = rsqrtf(s1);
        float mr0 = p0*inv0, mi0 = q0*inv0;
        float mr1 = p1*inv1, mi1 = q1*inv1;
        float sq0, cq0, sq1, cq1;
        sincosf(ph0 + bf2f(qav.x), &sq0, &cq0);
        sincosf(ph1 + bf2f(qav.y), &sq1, &cq1);
        float rr0 = mr0*cq0 + mi0*sq0, ri0 = mi0*cq0 - mr0*sq0;
        float rr1 = mr1*cq1 + mi1*sq1, ri1 = mi1*cq1 - mr1*sq1;
        ushort2 rv;
        rv.x = f2bf(bf2f(mrv.x)*rr0 + bf2f(miv.x)*ri0);
        rv.y = f2bf(bf2f(mrv.y)*rr1 + bf2f(miv.y)*ri1);
        *(ushort2*)(ret + o) = rv;
    }
}

// LayerNorm over d per row; bf16 in/out, ushort4 vectorized
__global__ __launch_bounds__(256) void ln_k(
    const ushort* __restrict__ ret, const float* __restrict__ ln_g,
    const float* __restrict__ ln_b, ushort* __restrict__ outp)
{
    int row = blockIdx.x;
    size_t base = (size_t)row*DD;
    int d0 = threadIdx.x*4;
    ushort4 rv = *(const ushort4*)(ret + base + d0);
    float v0 = bf2f(rv.x), v1 = bf2f(rv.y), v2 = bf2f(rv.z), v3 = bf2f(rv.w);
    float sum = v0+v1+v2+v3;
    float sumsq = v0*v0 + v1*v1 + v2*v2 + v3*v3;
    #pragma unroll
    for (int off=32; off; off>>=1){
        sum   += __shfl_down(sum,off);
        sumsq += __shfl_down(sumsq,off);
    }
    __shared__ float red[8];
    int lane = threadIdx.x & 63, wid = threadIdx.x >> 6;
    if (lane==0){ red[wid]=sum; red[4+wid]=sumsq; }
    __syncthreads();
    sum   = red[0]+red[1]+red[2]+red[3];
    sumsq = red[4]+red[5]+red[6]+red[7];
    float mu  = sum * (1.0f/DD);
    float var = sumsq*(1.0f/DD) - mu*mu;
    float rstd = rsqrtf(var + 1e-5f);
    float4 g = *(const float4*)(ln_g + d0);
    float4 bb = *(const float4*)(ln_b + d0);
    ushort4 ov;
    ov.x = f2bf((v0-mu)*rstd*g.x + bb.x);
    ov.y = f2bf((v1-mu)*rstd*g.y + bb.y);
    ov.z = f2bf((v2-mu)*rstd*g.z + bb.z);
    ov.w = f2bf((v3-mu)*rstd*g.w + bb.w);
    *(ushort4*)(outp + base + d0) = ov;
}

extern "C" void kernel_launch(void* const* d_in, const int* in_sizes, int n_in,
                              void* d_out, int out_size, void* d_ws, size_t ws_size,
                              hipStream_t stream)
{
    const float* x     = (const float*)d_in[0];
    const float* w_pt1 = (const float*)d_in[1];
    const float* b_pt1 = (const float*)d_in[2];
    const float* w_pt2 = (const float*)d_in[3];
    const float* b_pt2 = (const float*)d_in[4];
    const float* iscale= (const float*)d_in[5];
    const float* w_wg  = (const float*)d_in[6];
    const float* b_wg  = (const float*)d_in[7];
    const float* gtemp = (const float*)d_in[8];
    const float* w_mag = (const float*)d_in[9];
    const float* b_mag = (const float*)d_in[10];
    const float* w_q1  = (const float*)d_in[11];
    const float* b_q1  = (const float*)d_in[12];
    const float* w_q2  = (const float*)d_in[13];
    const float* b_q2  = (const float*)d_in[14];
    const float* w_mix = (const float*)d_in[15];
    const float* b_mix = (const float*)d_in[16];
    const float* ln_g  = (const float*)d_in[17];
    const float* ln_b  = (const float*)d_in[18];
    const float* w_o1  = (const float*)d_in[19];
    const float* b_o1  = (const float*)d_in[20];
    const float* w_o2  = (const float*)d_in[21];
    const float* b_o2  = (const float*)d_in[22];
    float* out = (float*)d_out;

    const size_t SZ = (size_t)MTOT*DD;     // 4M elems
    ushort* u = (ushort*)d_ws;
    ushort* xb    = u;                 u += SZ;        // bf16 x
    ushort* H1b   = u;                 u += 2*SZ;      // [4096][2048]
    ushort* ret   = H1b;                                // alias (H1b dead after BC)
    ushort* Hqb   = u;                 u += SZ;
    ushort* lnb   = Hqb;                                // alias (Hqb dead after BC)
    ushort* wgb   = u;                 u += SZ;
    ushort* magb  = u;                 u += SZ;
    ushort* mixb  = u;                 u += 2*SZ;      // [4096][2048]
    ushort* Hob   = u;                 u += SZ;
    ushort* pdb   = u;                 u += SZ;        // bf16
    ushort* qadjb = u;                 u += SZ;        // bf16
    ushort* Wt_all= u;                 u += (size_t)7168*1024;
    ushort* wt_pt2= u;                 u += (size_t)1024*2048;
    ushort* wt_q2 = u;                 u += (size_t)1024*1024;
    ushort* wt_o1 = u;                 u += (size_t)1024*1024;
    ushort* wt_o2 = u;                 u += (size_t)1024*1024;
    float* csum_phi = (float*)u;                       // BB*NC2*DD = 1MB
    float* csum_tri = csum_phi + (size_t)BB*NC2*DD;    // 3x

    dim3 blk(256);
    // conversions
    cvt_bf16_k<<<dim3(SZ/2048), blk, 0, stream>>>(x, xb);
    tcvt_all_k<<<dim3(12288), blk, 0, stream>>>(w_pt1, w_mix, w_wg, w_mag, w_q1, w_q2,
                                                w_o1, w_o2, w_pt2,
                                                Wt_all, wt_q2, wt_o1, wt_o2, wt_pt2);
    // fused GEMM A (1792 blocks, XCD-chunked, r6 128^2 core)
    mgemmA_k<<<dim3(1792), blk, 0, stream>>>(xb, Wt_all, b_pt1, b_wg, b_mag, b_q1, b_mix,
                                             gtemp, H1b, wgb, magb, Hqb, mixb);
    // GEMM B/C (512 blocks) + fused phi chunk sums
    mgemmBC_k<<<dim3(512), blk, 0, stream>>>(H1b, wt_pt2, Hqb, wt_q2, b_pt2, b_q2,
                                             iscale, pdb, qadjb, csum_phi);
    // scan complex
    scan2_k<<<dim3((BB*DD+255)/256), blk, 0, stream>>>(csum_phi, BB*DD);
    passB_k<<<dim3(DD/512, NC2, BB), blk, 0, stream>>>(pdb, wgb, magb, xb, csum_phi, csum_tri);
    scan2_k<<<dim3((3*BB*DD+255)/256), blk, 0, stream>>>(csum_tri, 3*BB*DD);
    passC_k<<<dim3(DD/512, NC2, BB), blk, 0, stream>>>(pdb, wgb, magb, xb, qadjb, mixb,
                                                       csum_phi, csum_tri, ret);
    ln_k<<<dim3(MTOT), blk, 0, stream>>>(ret, ln_g, ln_b, lnb);
    // output head (256 blocks each)
    mgemm_k<1,false,true><<<dim3(256), blk, 0, stream>>>(lnb, wt_o1, b_o1, nullptr, Hob, DD, DD);
    mgemm_k<0,true,false><<<dim3(256), blk, 0, stream>>>(Hob, wt_o2, b_o2, x, out, DD, DD);
}